// Round 3
// baseline (535.324 us; speedup 1.0000x reference)
//
#include <hip/hip_runtime.h>

typedef unsigned short u16;
typedef unsigned int u32;
typedef __bf16 bf16x8 __attribute__((ext_vector_type(8)));
typedef float f32x4 __attribute__((ext_vector_type(4)));

#define SEQ 2048
#define NH 16
#define ATT_SCALE 0.125f

__device__ __forceinline__ u16 f2bf(float f) {
  union { float f; u32 u; } v; v.f = f;
  u32 r = v.u + 0x7fffu + ((v.u >> 16) & 1u);
  return (u16)(r >> 16);
}

typedef __attribute__((address_space(3))) u32 as3_u32;
typedef __attribute__((address_space(1))) const u32 as1_u32;

__device__ __forceinline__ void gload_lds16(const void* g, void* l) {
  __builtin_amdgcn_global_load_lds((as1_u32*)g, (as3_u32*)l, 16, 0, 0);
}

// ---------------- fp32 -> bf16 convert (vectorized) ----------------
__global__ __launch_bounds__(256) void cvt_bf16(const float* __restrict__ in,
                                                u16* __restrict__ out) {
  int i = blockIdx.x * 256 + threadIdx.x;
  float4 v = ((const float4*)in)[i];
  uint2 o;
  o.x = (u32)f2bf(v.x) | ((u32)f2bf(v.y) << 16);
  o.y = (u32)f2bf(v.z) | ((u32)f2bf(v.w) << 16);
  ((uint2*)out)[i] = o;
}

// ---------------- transpose + convert: in fp32 [R][C] -> out bf16 [C][R] ----
__global__ __launch_bounds__(256) void transpose_cvt(const float* __restrict__ in,
                                                     u16* __restrict__ out,
                                                     int R, int C) {
  __shared__ float tile[32][33];
  int x = blockIdx.x * 32 + threadIdx.x;  // col
  int y0 = blockIdx.y * 32;               // row base
#pragma unroll
  for (int j = 0; j < 32; j += 8)
    tile[threadIdx.y + j][threadIdx.x] = in[(size_t)(y0 + threadIdx.y + j) * C + x];
  __syncthreads();
  int ox = y0 + threadIdx.x;  // out col = old row
#pragma unroll
  for (int j = 0; j < 32; j += 8) {
    int oy = blockIdx.x * 32 + threadIdx.y + j;  // out row = old col
    out[(size_t)oy * R + ox] = f2bf(tile[threadIdx.x][threadIdx.y + j]);
  }
}

// ---------------- bf16 GEMM, 128x128 tile, BK=32, 4 waves ----------------
// A: [M][K] bf16 row-major.  B: [N][K] bf16 row-major (i.e. W transposed).
// MODE 0: Cout = float [M][N].
// MODE 1: per-head L2 normalize (head = 64 cols) then bf16 out [head][SEQ][64].
template <int MODE>
__global__ __launch_bounds__(256) void gemm_bf16(const u16* __restrict__ A,
                                                 const u16* __restrict__ B,
                                                 void* __restrict__ Cout,
                                                 int M, int N, int K) {
  __shared__ u16 Al[128 * 32];
  __shared__ u16 Bl[128 * 32];
  const int tid = threadIdx.x;
  const int w = tid >> 6, lane = tid & 63, g = lane >> 4, c16 = lane & 15;
  const int wr = w >> 1, wc = w & 1;
  const int brow = blockIdx.y * 128, bcol = blockIdx.x * 128;
  f32x4 acc[4][4] = {};
  const int nk = K >> 5;
  for (int kt = 0; kt < nk; ++kt) {
#pragma unroll
    for (int r2 = 0; r2 < 2; ++r2) {
      int c = w * 64 + r2 * 256 + lane;
      int row = c >> 2, slot = c & 3;
      const u16* ga = A + (size_t)(brow + row) * K + kt * 32 + ((slot ^ (row & 3)) << 3);
      gload_lds16(ga, &Al[(w * 64 + r2 * 256) * 8]);
      const u16* gb = B + (size_t)(bcol + row) * K + kt * 32 + ((slot ^ (row & 3)) << 3);
      gload_lds16(gb, &Bl[(w * 64 + r2 * 256) * 8]);
    }
    __syncthreads();
    bf16x8 af[4], bfv[4];
#pragma unroll
    for (int m = 0; m < 4; ++m) {
      int row = wr * 64 + m * 16 + c16;
      af[m] = *(const bf16x8*)&Al[row * 32 + ((g * 8) ^ ((row & 3) << 3))];
    }
#pragma unroll
    for (int n = 0; n < 4; ++n) {
      int row = wc * 64 + n * 16 + c16;
      bfv[n] = *(const bf16x8*)&Bl[row * 32 + ((g * 8) ^ ((row & 3) << 3))];
    }
#pragma unroll
    for (int m = 0; m < 4; ++m)
#pragma unroll
      for (int n = 0; n < 4; ++n)
        acc[m][n] = __builtin_amdgcn_mfma_f32_16x16x32_bf16(af[m], bfv[n], acc[m][n], 0, 0, 0);
    __syncthreads();
  }
  if constexpr (MODE == 1) {
    u16* On = (u16*)Cout;
    int head = blockIdx.x * 2 + wc;
#pragma unroll
    for (int m = 0; m < 4; ++m) {
#pragma unroll
      for (int r = 0; r < 4; ++r) {
        int grow = brow + wr * 64 + m * 16 + g * 4 + r;
        float ss = 0.f;
#pragma unroll
        for (int n = 0; n < 4; ++n) ss += acc[m][n][r] * acc[m][n][r];
        ss += __shfl_xor(ss, 1);
        ss += __shfl_xor(ss, 2);
        ss += __shfl_xor(ss, 4);
        ss += __shfl_xor(ss, 8);
        float sc = 1.0f / (sqrtf(ss) + 1e-6f);
#pragma unroll
        for (int n = 0; n < 4; ++n)
          On[((size_t)head * SEQ + grow) * 64 + n * 16 + c16] = f2bf(acc[m][n][r] * sc);
      }
    }
  } else {
    float* Cf = (float*)Cout;
#pragma unroll
    for (int m = 0; m < 4; ++m)
#pragma unroll
      for (int r = 0; r < 4; ++r)
#pragma unroll
        for (int n = 0; n < 4; ++n)
          Cf[(size_t)(brow + wr * 64 + m * 16 + g * 4 + r) * N + bcol + wc * 64 + n * 16 + c16] =
              acc[m][n][r];
  }
}

// ---------------- fused flash attention with additive bias ----------------
// Qn,Kn: [h][SEQ][64] bf16 (L2-normalized).  Vt: [h][64][SEQ] bf16.
// bias: [h][SEQ][SEQ] fp32.  At out: [SEQ][1024] bf16 (row = q, col = h*64+d).
__global__ __launch_bounds__(256) void attn_fused(const u16* __restrict__ Qn,
                                                  const u16* __restrict__ Kn,
                                                  const u16* __restrict__ Vt,
                                                  const float* __restrict__ bias,
                                                  u16* __restrict__ At) {
  __shared__ u16 Kl[64 * 64];
  __shared__ u16 Vl[64 * 64];
  __shared__ u16 Pl[64 * 64];
  const int tid = threadIdx.x;
  const int w = tid >> 6, lane = tid & 63, g = lane >> 4, c16 = lane & 15;
  const int h = blockIdx.y;
  const int qbase = blockIdx.x * 64;

  bf16x8 qf[2];
  {
    int qrow = qbase + w * 16 + c16;
    const u16* qp = Qn + ((size_t)h * SEQ + qrow) * 64 + g * 8;
    qf[0] = *(const bf16x8*)qp;
    qf[1] = *(const bf16x8*)(qp + 32);
  }
  f32x4 oacc[4] = {};
  float mrow[4] = {-1e30f, -1e30f, -1e30f, -1e30f};
  float lsum[4] = {0.f, 0.f, 0.f, 0.f};

  for (int kt = 0; kt < 32; ++kt) {
    // stage K tile [key][d] and V tile [d][key] (both swizzled via source)
#pragma unroll
    for (int r2 = 0; r2 < 2; ++r2) {
      int c = w * 64 + r2 * 256 + lane;
      int row = c >> 3, slot = c & 7;
      const u16* gk = Kn + ((size_t)h * SEQ + kt * 64 + row) * 64 + ((slot ^ (row & 7)) << 3);
      gload_lds16(gk, &Kl[(w * 64 + r2 * 256) * 8]);
      const u16* gv = Vt + ((size_t)h * 64 + row) * SEQ + kt * 64 + ((slot ^ (row & 7)) << 3);
      gload_lds16(gv, &Vl[(w * 64 + r2 * 256) * 8]);
    }
    // bias -> regs (overlaps staging; barrier drains all)
    float bb[4][4];
#pragma unroll
    for (int st = 0; st < 4; ++st)
#pragma unroll
      for (int r = 0; r < 4; ++r) {
        int qr = qbase + w * 16 + g * 4 + r;
        int kc = kt * 64 + st * 16 + c16;
        bb[st][r] = bias[((size_t)h * SEQ + qr) * SEQ + kc];
      }
    __syncthreads();

    // S = Qn . Kn^T  (per wave: 16 q-rows x 64 keys)
    f32x4 s[4] = {};
#pragma unroll
    for (int ch = 0; ch < 2; ++ch)
#pragma unroll
      for (int st = 0; st < 4; ++st) {
        int krow = st * 16 + c16;
        bf16x8 kf = *(const bf16x8*)&Kl[krow * 64 + ((ch * 32 + g * 8) ^ ((krow & 7) << 3))];
        s[st] = __builtin_amdgcn_mfma_f32_16x16x32_bf16(qf[ch], kf, s[st], 0, 0, 0);
      }

    // online softmax (fp32), P -> LDS (bf16, swizzled)
#pragma unroll
    for (int r = 0; r < 4; ++r) {
      float lg0 = s[0][r] * ATT_SCALE + bb[0][r];
      float lg1 = s[1][r] * ATT_SCALE + bb[1][r];
      float lg2 = s[2][r] * ATT_SCALE + bb[2][r];
      float lg3 = s[3][r] * ATT_SCALE + bb[3][r];
      float mx = fmaxf(fmaxf(lg0, lg1), fmaxf(lg2, lg3));
      mx = fmaxf(mx, __shfl_xor(mx, 1));
      mx = fmaxf(mx, __shfl_xor(mx, 2));
      mx = fmaxf(mx, __shfl_xor(mx, 4));
      mx = fmaxf(mx, __shfl_xor(mx, 8));
      float mnew = fmaxf(mrow[r], mx);
      float corr = __expf(mrow[r] - mnew);
      mrow[r] = mnew;
      float p0 = __expf(lg0 - mnew), p1 = __expf(lg1 - mnew);
      float p2 = __expf(lg2 - mnew), p3 = __expf(lg3 - mnew);
      float ps = p0 + p1 + p2 + p3;
      ps += __shfl_xor(ps, 1);
      ps += __shfl_xor(ps, 2);
      ps += __shfl_xor(ps, 4);
      ps += __shfl_xor(ps, 8);
      lsum[r] = lsum[r] * corr + ps;
#pragma unroll
      for (int st = 0; st < 4; ++st) oacc[st][r] *= corr;
      int prow = w * 16 + g * 4 + r;
      int sw = (prow & 7) << 3;
      Pl[prow * 64 + ((0 * 16 + c16) ^ sw)] = f2bf(p0);
      Pl[prow * 64 + ((1 * 16 + c16) ^ sw)] = f2bf(p1);
      Pl[prow * 64 + ((2 * 16 + c16) ^ sw)] = f2bf(p2);
      Pl[prow * 64 + ((3 * 16 + c16) ^ sw)] = f2bf(p3);
    }

    // O += P . V  (A from Pl, B from Vl)
#pragma unroll
    for (int ch = 0; ch < 2; ++ch) {
      int arow = w * 16 + c16;
      bf16x8 pa = *(const bf16x8*)&Pl[arow * 64 + ((ch * 32 + g * 8) ^ ((arow & 7) << 3))];
#pragma unroll
      for (int st = 0; st < 4; ++st) {
        int vrow = st * 16 + c16;
        bf16x8 vf = *(const bf16x8*)&Vl[vrow * 64 + ((ch * 32 + g * 8) ^ ((vrow & 7) << 3))];
        oacc[st] = __builtin_amdgcn_mfma_f32_16x16x32_bf16(pa, vf, oacc[st], 0, 0, 0);
      }
    }
    __syncthreads();
  }

  // epilogue: normalize by lsum, write attended bf16 [q][h*64+d]
#pragma unroll
  for (int r = 0; r < 4; ++r) {
    float inv = 1.0f / lsum[r];
    int qr = qbase + w * 16 + g * 4 + r;
#pragma unroll
    for (int st = 0; st < 4; ++st)
      At[(size_t)qr * 1024 + h * 64 + st * 16 + c16] = f2bf(oacc[st][r] * inv);
  }
}

// ---------------- launch ----------------
extern "C" void kernel_launch(void* const* d_in, const int* in_sizes, int n_in,
                              void* d_out, int out_size, void* d_ws, size_t ws_size,
                              hipStream_t stream) {
  const float* Qin = (const float*)d_in[0];
  const float* Kin = (const float*)d_in[1];
  const float* Vin = (const float*)d_in[2];
  const float* bias = (const float*)d_in[3];
  const float* Wq = (const float*)d_in[4];
  const float* Wk = (const float*)d_in[5];
  const float* Wv = (const float*)d_in[6];
  const float* Wo = (const float*)d_in[7];
  float* out = (float*)d_out;

  char* ws = (char*)d_ws;
  const size_t MB = 1024 * 1024;
  u16* bfQ = (u16*)(ws + 0 * MB);
  u16* bfK = (u16*)(ws + 4 * MB);
  u16* bfV = (u16*)(ws + 8 * MB);
  u16* WqT = (u16*)(ws + 12 * MB);
  u16* WkT = (u16*)(ws + 14 * MB);
  u16* WvT = (u16*)(ws + 16 * MB);
  u16* WoT = (u16*)(ws + 18 * MB);
  u16* Qn = (u16*)(ws + 20 * MB);
  u16* Kn = (u16*)(ws + 24 * MB);
  u16* Vt = (u16*)(ws + 28 * MB);
  float* Vp = (float*)(ws + 32 * MB);
  u16* At = (u16*)(ws + 40 * MB);

  // 1) convert inputs to bf16
  cvt_bf16<<<2048, 256, 0, stream>>>(Qin, bfQ);
  cvt_bf16<<<2048, 256, 0, stream>>>(Kin, bfK);
  cvt_bf16<<<2048, 256, 0, stream>>>(Vin, bfV);

  // 2) transpose+convert weights to bf16 [N][K]
  dim3 tb(32, 8);
  transpose_cvt<<<dim3(32, 32), tb, 0, stream>>>(Wq, WqT, 1024, 1024);
  transpose_cvt<<<dim3(32, 32), tb, 0, stream>>>(Wk, WkT, 1024, 1024);
  transpose_cvt<<<dim3(32, 32), tb, 0, stream>>>(Wv, WvT, 1024, 1024);
  transpose_cvt<<<dim3(32, 32), tb, 0, stream>>>(Wo, WoT, 1024, 1024);

  // 3) projections (Q,K fused L2-norm epilogue -> per-head bf16; V plain fp32)
  gemm_bf16<1><<<dim3(8, 16), 256, 0, stream>>>(bfQ, WqT, Qn, 2048, 1024, 1024);
  gemm_bf16<1><<<dim3(8, 16), 256, 0, stream>>>(bfK, WkT, Kn, 2048, 1024, 1024);
  gemm_bf16<0><<<dim3(8, 16), 256, 0, stream>>>(bfV, WvT, Vp, 2048, 1024, 1024);

  // 4) V -> transposed per-head layout Vt[h*64+d][sq]
  transpose_cvt<<<dim3(32, 64), tb, 0, stream>>>(Vp, Vt, 2048, 1024);

  // 5) fused attention with bias
  attn_fused<<<dim3(32, 16), 256, 0, stream>>>(Qn, Kn, Vt, bias, At);

  // 6) output projection -> fp32 out
  gemm_bf16<0><<<dim3(8, 16), 256, 0, stream>>>(At, WoT, out, 2048, 1024, 1024);
}